// Round 13
// baseline (308.208 us; speedup 1.0000x reference)
//
#include <hip/hip_runtime.h>
#include <hip/hip_fp16.h>

#define BB 16
#define HH 128
#define WW 128
#define CC 256

typedef __attribute__((ext_vector_type(8))) short s16x8;
typedef __attribute__((ext_vector_type(8))) unsigned short u16x8;
typedef __attribute__((ext_vector_type(4))) float f32x4;
typedef __attribute__((ext_vector_type(4))) int i32x4;

__device__ static inline unsigned short f2bf(float x) {
    union { float f; unsigned u; } v; v.f = x;
    unsigned r = v.u + 0x7fffu + ((v.u >> 16) & 1u);  // RNE
    return (unsigned short)(r >> 16);
}
__device__ static inline float bf2f(unsigned short u) {
    union { unsigned u; float f; } v; v.u = (unsigned)u << 16; return v.f;
}
__device__ static inline unsigned short h2u(__half h) {
    unsigned short u; __builtin_memcpy(&u, &h, 2); return u;
}
__device__ static inline float u2f16(unsigned short u) {
    __half h; __builtin_memcpy(&h, &u, 2); return __half2float(h);
}
// swizzled halfword index into [128 row][256 col] LDS tile (16B-chunk XOR)
__device__ static inline int sidx(int row, int col) {
    return row * 256 + (((col >> 3) ^ (row & 7)) << 3) + (col & 7);
}
// same, 8B granularity: c4 covers cols c4*4 .. c4*4+3
__device__ static inline int sidx4(int row, int c4) {
    return row * 256 + (((c4 >> 1) ^ (row & 7)) << 3) + (c4 & 1) * 4;
}

// ---- W[512,256] f32 -> two k-grouped bf16 tables (x: k<256, y: k>=256)
__global__ __launch_bounds__(256) void conv_w_kernel(const float* __restrict__ Wf,
                                                     unsigned short* __restrict__ Wt) {
    const int i = blockIdx.x * 256 + threadIdx.x;   // i = k*256+n
    const int n = i & 255, k = i >> 8;
    const int hy = k >> 8, g = (k >> 3) & 31, j = k & 7;
    Wt[hy * 65536 + ((size_t)(g * 256 + n) << 3) + j] = f2bf(Wf[i]);
}

// ---- scan 16 rows (seg s) of 4 channels (c4) into swizzled LDS; seg-max out.
__device__ __forceinline__ void scan16_to_lds(const float4* __restrict__ base, size_t st,
                                              unsigned short* __restrict__ As,
                                              unsigned short* __restrict__ smax,
                                              int c4, int s) {
    const int row0 = s * 16;
    float4 buf[8], nxt[8];
    #pragma unroll
    for (int j = 0; j < 8; ++j) buf[j] = base[(size_t)j * st];
    __builtin_amdgcn_sched_group_barrier(0x20, 8, 0);
    #pragma unroll
    for (int j = 0; j < 8; ++j) nxt[j] = base[(size_t)(8 + j) * st];
    __builtin_amdgcn_sched_group_barrier(0x20, 8, 0);
    float4 run = make_float4(-3.4e38f, -3.4e38f, -3.4e38f, -3.4e38f);
    #pragma unroll
    for (int j = 0; j < 8; ++j) {
        run.x = fmaxf(run.x, buf[j].x); run.y = fmaxf(run.y, buf[j].y);
        run.z = fmaxf(run.z, buf[j].z); run.w = fmaxf(run.w, buf[j].w);
        ushort4 o; o.x = f2bf(run.x); o.y = f2bf(run.y); o.z = f2bf(run.z); o.w = f2bf(run.w);
        *(ushort4*)(As + sidx4(row0 + j, c4)) = o;
    }
    #pragma unroll
    for (int j = 0; j < 8; ++j) {
        run.x = fmaxf(run.x, nxt[j].x); run.y = fmaxf(run.y, nxt[j].y);
        run.z = fmaxf(run.z, nxt[j].z); run.w = fmaxf(run.w, nxt[j].w);
        ushort4 o; o.x = f2bf(run.x); o.y = f2bf(run.y); o.z = f2bf(run.z); o.w = f2bf(run.w);
        *(ushort4*)(As + sidx4(row0 + 8 + j, c4)) = o;
    }
    ushort4 sm; sm.x = f2bf(run.x); sm.y = f2bf(run.y); sm.z = f2bf(run.z); sm.w = f2bf(run.w);
    *(ushort4*)(smax + s * 256 + c4 * 4) = sm;
}

// ---- apply prefix carry (seg-maxes 0..s-1) to this thread's 16 rows
__device__ __forceinline__ void carry_apply(unsigned short* __restrict__ As,
                                            const unsigned short* __restrict__ smax,
                                            int c4, int s) {
    if (s == 0) return;   // s is wave-uniform -> no divergence
    float4 cf = make_float4(-3.4e38f, -3.4e38f, -3.4e38f, -3.4e38f);
    for (int k = 0; k < s; ++k) {
        const ushort4 m = *(const ushort4*)(smax + k * 256 + c4 * 4);
        cf.x = fmaxf(cf.x, bf2f(m.x)); cf.y = fmaxf(cf.y, bf2f(m.y));
        cf.z = fmaxf(cf.z, bf2f(m.z)); cf.w = fmaxf(cf.w, bf2f(m.w));
    }
    ushort4 cb; cb.x = f2bf(cf.x); cb.y = f2bf(cf.y); cb.z = f2bf(cf.z); cb.w = f2bf(cf.w);
    const int row0 = s * 16;
    #pragma unroll
    for (int r = 0; r < 16; ++r) {
        unsigned short* pp = As + sidx4(row0 + r, c4);
        ushort4 v = *(ushort4*)(pp);
        ushort4 o;
        o.x = (bf2f(v.x) >= cf.x) ? v.x : cb.x;
        o.y = (bf2f(v.y) >= cf.y) ? v.y : cb.y;
        o.z = (bf2f(v.z) >= cf.z) ? v.z : cb.z;
        o.w = (bf2f(v.w) >= cf.w) ? v.w : cb.w;
        *(ushort4*)(pp) = o;
    }
}

// ---- GEMM C[128x256] = As(bf16,swz) @ Wv, stage C as f16 back into As.
// 8 waves: wr = wid>>2 (2 row-tiles of 64), wn = wid&3 (4 col-tiles of 64).
__device__ __forceinline__ void gemm_stage(unsigned short* __restrict__ As,
                                           const s16x8* __restrict__ Wv, int t) {
    const int lane = t & 63, wid = t >> 6;
    const int wr = wid >> 2, wn = wid & 3;
    f32x4 acc[4][4];
    #pragma unroll
    for (int i = 0; i < 4; ++i)
        #pragma unroll
        for (int j = 0; j < 4; ++j) acc[i][j] = (f32x4){0.f, 0.f, 0.f, 0.f};

    #pragma unroll
    for (int q = 0; q < 8; ++q) {
        const int g = q * 4 + (lane >> 4);     // 16B chunk index, 0..31
        s16x8 af[4], bf[4];
        #pragma unroll
        for (int fm = 0; fm < 4; ++fm) {
            const int row = wr * 64 + fm * 16 + (lane & 15);
            af[fm] = *(const s16x8*)(As + row * 256 + ((g ^ (row & 7)) << 3));
        }
        #pragma unroll
        for (int fn = 0; fn < 4; ++fn)
            bf[fn] = Wv[g * 256 + wn * 64 + fn * 16 + (lane & 15)];
        #pragma unroll
        for (int fm = 0; fm < 4; ++fm)
            #pragma unroll
            for (int fn = 0; fn < 4; ++fn)
                acc[fm][fn] = __builtin_amdgcn_mfma_f32_16x16x32_bf16(
                    af[fm], bf[fn], acc[fm][fn], 0, 0, 0);
    }
    __syncthreads();   // all As reads done before overwrite
    #pragma unroll
    for (int fn = 0; fn < 4; ++fn) {
        const int col = wn * 64 + fn * 16 + (lane & 15);
        #pragma unroll
        for (int fm = 0; fm < 4; ++fm) {
            const int rbase = wr * 64 + fm * 16 + ((lane >> 4) << 2);
            #pragma unroll
            for (int r = 0; r < 4; ++r)
                As[sidx(rbase + r, col)] = h2u(__float2half(acc[fm][fn][r]));
        }
    }
    __syncthreads();
}

// ---- K1: h-scan + GEMM(Wy) -> partial f16 (layout b,h,w,c). Block = (b,w).
// (unchanged from r8 best)
__global__ __launch_bounds__(512, 4) void hscan_gemm_kernel(const float* __restrict__ grid,
                                                            const unsigned short* __restrict__ Wt,
                                                            unsigned short* __restrict__ partial) {
    __shared__ unsigned short As[32768];   // [128][256] bf16, swizzled
    __shared__ unsigned short smax[2048];  // [8 seg][256 c]
    const int t = threadIdx.x;
    const int c4 = t & 63, s = t >> 6;
    const int b = blockIdx.x >> 7;
    const int w = blockIdx.x & 127;

    // rows = h; float4 row stride = 128*256/4 = 8192
    const float4* base = (const float4*)(grid + ((size_t)(b * 128 + s * 16) * 128 + w) * 256) + c4;
    scan16_to_lds(base, 8192, As, smax, c4, s);
    __syncthreads();
    carry_apply(As, smax, c4, s);
    __syncthreads();

    gemm_stage(As, (const s16x8*)(Wt + 65536), t);   // Wy table

    // drain: partial[((b*128+h)*128 + w)*256 + col], 16B/lane
    #pragma unroll
    for (int it = 0; it < 8; ++it) {
        const int f = it * 4096 + t * 8;
        const int row = f >> 8, col = f & 255;     // row = h
        const i32x4 v = *(const i32x4*)(As + sidx(row, col));
        *(i32x4*)(partial + (((size_t)b * 128 + row) * 128 + w) * 256 + col) = v;
    }
}

// ---- K2: w-scan + GEMM(Wx) + partial + bias -> out f32. Block = (b,h).
// vs r8: NO stage/drain LDS round-trip. Epilogue adds partial+bias directly
// to acc and stores f32 from registers (64-B segment pattern, verified r0-r6).
// 64 independent scalar partial loads -> MLP 64, one latency exposure.
__global__ __launch_bounds__(512, 4) void wscan_gemm_kernel(const float* __restrict__ grid,
                                                            const unsigned short* __restrict__ Wt,
                                                            const unsigned short* __restrict__ partial,
                                                            const float* __restrict__ bias,
                                                            float* __restrict__ out) {
    __shared__ unsigned short As[32768];
    __shared__ unsigned short smax[2048];
    const int t = threadIdx.x;
    const int c4 = t & 63, s = t >> 6;
    const size_t bh = blockIdx.x;       // b*128 + h

    // rows = w; float4 row stride = 256/4 = 64
    const float4* base = (const float4*)(grid + (bh * 128 + (size_t)(s * 16)) * 256) + c4;
    scan16_to_lds(base, 64, As, smax, c4, s);
    __syncthreads();
    carry_apply(As, smax, c4, s);
    __syncthreads();

    // GEMM (same fragment math as gemm_stage), no re-stage
    const s16x8* Wv = (const s16x8*)Wt;             // Wx table
    const int lane = t & 63, wid = t >> 6;
    const int wr = wid >> 2, wn = wid & 3;
    f32x4 acc[4][4];
    #pragma unroll
    for (int i = 0; i < 4; ++i)
        #pragma unroll
        for (int j = 0; j < 4; ++j) acc[i][j] = (f32x4){0.f, 0.f, 0.f, 0.f};

    #pragma unroll
    for (int q = 0; q < 8; ++q) {
        const int g = q * 4 + (lane >> 4);
        s16x8 af[4], bf[4];
        #pragma unroll
        for (int fm = 0; fm < 4; ++fm) {
            const int row = wr * 64 + fm * 16 + (lane & 15);
            af[fm] = *(const s16x8*)(As + row * 256 + ((g ^ (row & 7)) << 3));
        }
        #pragma unroll
        for (int fn = 0; fn < 4; ++fn)
            bf[fn] = Wv[g * 256 + wn * 64 + fn * 16 + (lane & 15)];
        #pragma unroll
        for (int fm = 0; fm < 4; ++fm)
            #pragma unroll
            for (int fn = 0; fn < 4; ++fn)
                acc[fm][fn] = __builtin_amdgcn_mfma_f32_16x16x32_bf16(
                    af[fm], bf[fn], acc[fm][fn], 0, 0, 0);
    }

    // epilogue: out = acc + partial + bias, direct from registers.
    // C/D layout: col = lane&15 (+16*fn), row = (lane>>4)*4 + r  [verified r0]
    #pragma unroll
    for (int fn = 0; fn < 4; ++fn) {
        const int col = wn * 64 + fn * 16 + (lane & 15);
        const float bb = bias[col];
        #pragma unroll
        for (int fm = 0; fm < 4; ++fm) {
            const int rbase = wr * 64 + fm * 16 + ((lane >> 4) << 2);
            #pragma unroll
            for (int r = 0; r < 4; ++r) {
                const size_t gi = (bh * 128 + (size_t)(rbase + r)) * 256 + col;
                const float o = acc[fm][fn][r] + u2f16(partial[gi]) + bb;
                __builtin_nontemporal_store(o, out + gi);
            }
        }
    }
}

extern "C" void kernel_launch(void* const* d_in, const int* in_sizes, int n_in,
                              void* d_out, int out_size, void* d_ws, size_t ws_size,
                              hipStream_t stream) {
    const float* grid = (const float*)d_in[0];
    const float* Wf   = (const float*)d_in[1];
    const float* bias = (const float*)d_in[2];
    float* out        = (float*)d_out;

    // workspace: partial f16 [M,256] = 128 MB (layout b,h,w,c), then Wt 256 KB
    unsigned short* partial = (unsigned short*)d_ws;
    unsigned short* Wt      = (unsigned short*)((char*)d_ws + (size_t)134217728);

    conv_w_kernel<<<512, 256, 0, stream>>>(Wf, Wt);
    hscan_gemm_kernel<<<2048, 512, 0, stream>>>(grid, Wt, partial);
    wscan_gemm_kernel<<<2048, 512, 0, stream>>>(grid, Wt, partial, bias, out);
}

// Round 15
// 215.074 us; speedup vs baseline: 1.4330x; 1.4330x over previous
//
#include <hip/hip_runtime.h>
#include <hip/hip_fp16.h>

#define BB 16
#define HH 128
#define WW 128
#define CC 256

typedef __attribute__((ext_vector_type(8))) short s16x8;
typedef __attribute__((ext_vector_type(8))) unsigned short u16x8;
typedef __attribute__((ext_vector_type(4))) float f32x4;
typedef __attribute__((ext_vector_type(4))) int i32x4;

__device__ static inline unsigned short f2bf(float x) {
    union { float f; unsigned u; } v; v.f = x;
    unsigned r = v.u + 0x7fffu + ((v.u >> 16) & 1u);  // RNE
    return (unsigned short)(r >> 16);
}
__device__ static inline float bf2f(unsigned short u) {
    union { unsigned u; float f; } v; v.u = (unsigned)u << 16; return v.f;
}
__device__ static inline unsigned short h2u(__half h) {
    unsigned short u; __builtin_memcpy(&u, &h, 2); return u;
}
__device__ static inline float u2f16(unsigned short u) {
    __half h; __builtin_memcpy(&h, &u, 2); return __half2float(h);
}
// swizzled halfword index into [128 row][256 col] LDS tile (16B-chunk XOR)
__device__ static inline int sidx(int row, int col) {
    return row * 256 + (((col >> 3) ^ (row & 7)) << 3) + (col & 7);
}
// same, 8B granularity: c4 covers cols c4*4 .. c4*4+3
__device__ static inline int sidx4(int row, int c4) {
    return row * 256 + (((c4 >> 1) ^ (row & 7)) << 3) + (c4 & 1) * 4;
}

// ---- W[512,256] f32 -> two k-grouped bf16 tables (x: k<256, y: k>=256)
// SEPARATE dispatch: Wt producer must complete before K1 consumes it
// (r14 fused this into K1 -> dispatch-order race -> absmax 5.8. Guideline 16.)
__global__ __launch_bounds__(256) void conv_w_kernel(const float* __restrict__ Wf,
                                                     unsigned short* __restrict__ Wt) {
    const int i = blockIdx.x * 256 + threadIdx.x;   // i = k*256+n
    const int n = i & 255, k = i >> 8;
    const int hy = k >> 8, g = (k >> 3) & 31, j = k & 7;
    Wt[hy * 65536 + ((size_t)(g * 256 + n) << 3) + j] = f2bf(Wf[i]);
}

// ---- scan 16 rows (seg s) of 4 channels (c4) into swizzled LDS; seg-max out.
// st = row stride in f32x4 units. NT: use nontemporal loads (read-once data).
template <bool NT>
__device__ __forceinline__ void scan16_to_lds(const f32x4* __restrict__ base, size_t st,
                                              unsigned short* __restrict__ As,
                                              unsigned short* __restrict__ smax,
                                              int c4, int s) {
    const int row0 = s * 16;
    f32x4 buf[8], nxt[8];
    #pragma unroll
    for (int j = 0; j < 8; ++j)
        buf[j] = NT ? __builtin_nontemporal_load(base + (size_t)j * st)
                    : base[(size_t)j * st];
    __builtin_amdgcn_sched_group_barrier(0x20, 8, 0);
    #pragma unroll
    for (int j = 0; j < 8; ++j)
        nxt[j] = NT ? __builtin_nontemporal_load(base + (size_t)(8 + j) * st)
                    : base[(size_t)(8 + j) * st];
    __builtin_amdgcn_sched_group_barrier(0x20, 8, 0);
    f32x4 run = {-3.4e38f, -3.4e38f, -3.4e38f, -3.4e38f};
    #pragma unroll
    for (int j = 0; j < 8; ++j) {
        run[0] = fmaxf(run[0], buf[j][0]); run[1] = fmaxf(run[1], buf[j][1]);
        run[2] = fmaxf(run[2], buf[j][2]); run[3] = fmaxf(run[3], buf[j][3]);
        ushort4 o; o.x = f2bf(run[0]); o.y = f2bf(run[1]); o.z = f2bf(run[2]); o.w = f2bf(run[3]);
        *(ushort4*)(As + sidx4(row0 + j, c4)) = o;
    }
    #pragma unroll
    for (int j = 0; j < 8; ++j) {
        run[0] = fmaxf(run[0], nxt[j][0]); run[1] = fmaxf(run[1], nxt[j][1]);
        run[2] = fmaxf(run[2], nxt[j][2]); run[3] = fmaxf(run[3], nxt[j][3]);
        ushort4 o; o.x = f2bf(run[0]); o.y = f2bf(run[1]); o.z = f2bf(run[2]); o.w = f2bf(run[3]);
        *(ushort4*)(As + sidx4(row0 + 8 + j, c4)) = o;
    }
    ushort4 sm; sm.x = f2bf(run[0]); sm.y = f2bf(run[1]); sm.z = f2bf(run[2]); sm.w = f2bf(run[3]);
    *(ushort4*)(smax + s * 256 + c4 * 4) = sm;
}

// ---- apply prefix carry (seg-maxes 0..s-1) to this thread's 16 rows
__device__ __forceinline__ void carry_apply(unsigned short* __restrict__ As,
                                            const unsigned short* __restrict__ smax,
                                            int c4, int s) {
    if (s == 0) return;   // s is wave-uniform -> no divergence
    float4 cf = make_float4(-3.4e38f, -3.4e38f, -3.4e38f, -3.4e38f);
    for (int k = 0; k < s; ++k) {
        const ushort4 m = *(const ushort4*)(smax + k * 256 + c4 * 4);
        cf.x = fmaxf(cf.x, bf2f(m.x)); cf.y = fmaxf(cf.y, bf2f(m.y));
        cf.z = fmaxf(cf.z, bf2f(m.z)); cf.w = fmaxf(cf.w, bf2f(m.w));
    }
    ushort4 cb; cb.x = f2bf(cf.x); cb.y = f2bf(cf.y); cb.z = f2bf(cf.z); cb.w = f2bf(cf.w);
    const int row0 = s * 16;
    #pragma unroll
    for (int r = 0; r < 16; ++r) {
        unsigned short* pp = As + sidx4(row0 + r, c4);
        ushort4 v = *(ushort4*)(pp);
        ushort4 o;
        o.x = (bf2f(v.x) >= cf.x) ? v.x : cb.x;
        o.y = (bf2f(v.y) >= cf.y) ? v.y : cb.y;
        o.z = (bf2f(v.z) >= cf.z) ? v.z : cb.z;
        o.w = (bf2f(v.w) >= cf.w) ? v.w : cb.w;
        *(ushort4*)(pp) = o;
    }
}

// ---- GEMM C[128x256] = As(bf16,swz) @ Wv (+colbias), stage C as f16 into As.
// 8 waves: wr = wid>>2 (2 row-tiles of 64), wn = wid&3 (4 col-tiles of 64).
// ADD_BIAS: fold bias[col] into the staged f16 values (K1 path).
template <bool ADD_BIAS>
__device__ __forceinline__ void gemm_stage(unsigned short* __restrict__ As,
                                           const s16x8* __restrict__ Wv,
                                           const float* __restrict__ bias, int t) {
    const int lane = t & 63, wid = t >> 6;
    const int wr = wid >> 2, wn = wid & 3;
    float bb[4];
    if (ADD_BIAS) {
        #pragma unroll
        for (int fn = 0; fn < 4; ++fn)
            bb[fn] = bias[wn * 64 + fn * 16 + (lane & 15)];
    }
    f32x4 acc[4][4];
    #pragma unroll
    for (int i = 0; i < 4; ++i)
        #pragma unroll
        for (int j = 0; j < 4; ++j) acc[i][j] = (f32x4){0.f, 0.f, 0.f, 0.f};

    #pragma unroll
    for (int q = 0; q < 8; ++q) {
        const int g = q * 4 + (lane >> 4);     // 16B chunk index, 0..31
        s16x8 af[4], bf[4];
        #pragma unroll
        for (int fm = 0; fm < 4; ++fm) {
            const int row = wr * 64 + fm * 16 + (lane & 15);
            af[fm] = *(const s16x8*)(As + row * 256 + ((g ^ (row & 7)) << 3));
        }
        #pragma unroll
        for (int fn = 0; fn < 4; ++fn)
            bf[fn] = Wv[g * 256 + wn * 64 + fn * 16 + (lane & 15)];
        #pragma unroll
        for (int fm = 0; fm < 4; ++fm)
            #pragma unroll
            for (int fn = 0; fn < 4; ++fn)
                acc[fm][fn] = __builtin_amdgcn_mfma_f32_16x16x32_bf16(
                    af[fm], bf[fn], acc[fm][fn], 0, 0, 0);
    }
    __syncthreads();   // all As reads done before overwrite
    #pragma unroll
    for (int fn = 0; fn < 4; ++fn) {
        const int col = wn * 64 + fn * 16 + (lane & 15);
        #pragma unroll
        for (int fm = 0; fm < 4; ++fm) {
            const int rbase = wr * 64 + fm * 16 + ((lane >> 4) << 2);
            #pragma unroll
            for (int r = 0; r < 4; ++r) {
                const float v = ADD_BIAS ? acc[fm][fn][r] + bb[fn] : acc[fm][fn][r];
                As[sidx(rbase + r, col)] = h2u(__float2half(v));
            }
        }
    }
    __syncthreads();
}

// ---- K1: h-scan + GEMM(Wy) + bias -> partial f16 (layout b,h,w,c). Block = (b,w).
__global__ __launch_bounds__(512, 4) void hscan_gemm_kernel(const float* __restrict__ grid,
                                                            const float* __restrict__ bias,
                                                            const unsigned short* __restrict__ Wt,
                                                            unsigned short* __restrict__ partial) {
    __shared__ unsigned short As[32768];   // [128][256] bf16, swizzled
    __shared__ unsigned short smax[2048];  // [8 seg][256 c]
    const int t = threadIdx.x;
    const int c4 = t & 63, s = t >> 6;
    const int b = blockIdx.x >> 7;
    const int w = blockIdx.x & 127;

    // rows = h; f32x4 row stride = 128*256/4 = 8192
    const f32x4* base = (const f32x4*)(grid + ((size_t)(b * 128 + s * 16) * 128 + w) * 256) + c4;
    scan16_to_lds<false>(base, 8192, As, smax, c4, s);
    __syncthreads();
    carry_apply(As, smax, c4, s);
    __syncthreads();

    gemm_stage<true>(As, (const s16x8*)(Wt + 65536), bias, t);   // Wy + bias

    // drain: partial[((b*128+h)*128 + w)*256 + col], 16B/lane
    #pragma unroll
    for (int it = 0; it < 8; ++it) {
        const int f = it * 4096 + t * 8;
        const int row = f >> 8, col = f & 255;     // row = h
        const i32x4 v = *(const i32x4*)(As + sidx(row, col));
        *(i32x4*)(partial + (((size_t)b * 128 + row) * 128 + w) * 256 + col) = v;
    }
}

// ---- K2: w-scan + GEMM(Wx) + partial -> out f32. Block = (b,h).
// nt loads on grid (last use) & partial (read-once); nt stores on out.
__global__ __launch_bounds__(512, 4) void wscan_gemm_kernel(const float* __restrict__ grid,
                                                            const unsigned short* __restrict__ Wt,
                                                            const unsigned short* __restrict__ partial,
                                                            float* __restrict__ out) {
    __shared__ unsigned short As[32768];
    __shared__ unsigned short smax[2048];
    const int t = threadIdx.x;
    const int c4 = t & 63, s = t >> 6;
    const size_t bh = blockIdx.x;       // b*128 + h

    // rows = w; f32x4 row stride = 256/4 = 64
    const f32x4* base = (const f32x4*)(grid + (bh * 128 + (size_t)(s * 16)) * 256) + c4;
    scan16_to_lds<true>(base, 64, As, smax, c4, s);
    __syncthreads();
    carry_apply(As, smax, c4, s);
    __syncthreads();

    gemm_stage<false>(As, (const s16x8*)Wt, nullptr, t);         // Wx

    // drain: out = lds_f16 + partial_f16, fully coalesced, nt policy
    #pragma unroll
    for (int it = 0; it < 8; ++it) {
        const int f = it * 4096 + t * 8;
        const int row = f >> 8, col = f & 255;      // row = w
        const u16x8 lv = *(const u16x8*)(As + sidx(row, col));
        const size_t gi = bh * 32768 + (size_t)f;
        const u16x8 pv = __builtin_nontemporal_load((const u16x8*)(partial + gi));
        f32x4 o0, o1;
        #pragma unroll
        for (int k = 0; k < 4; ++k)
            o0[k] = u2f16((unsigned short)lv[k]) + u2f16((unsigned short)pv[k]);
        #pragma unroll
        for (int k = 0; k < 4; ++k)
            o1[k] = u2f16((unsigned short)lv[4 + k]) + u2f16((unsigned short)pv[4 + k]);
        __builtin_nontemporal_store(o0, (f32x4*)(out + gi));
        __builtin_nontemporal_store(o1, (f32x4*)(out + gi + 4));
    }
}

extern "C" void kernel_launch(void* const* d_in, const int* in_sizes, int n_in,
                              void* d_out, int out_size, void* d_ws, size_t ws_size,
                              hipStream_t stream) {
    const float* grid = (const float*)d_in[0];
    const float* Wf   = (const float*)d_in[1];
    const float* bias = (const float*)d_in[2];
    float* out        = (float*)d_out;

    // workspace: partial f16 [M,256] = 128 MB (layout b,h,w,c), then Wt 256 KB
    unsigned short* partial = (unsigned short*)d_ws;
    unsigned short* Wt      = (unsigned short*)((char*)d_ws + (size_t)134217728);

    conv_w_kernel<<<512, 256, 0, stream>>>(Wf, Wt);
    hscan_gemm_kernel<<<2048, 512, 0, stream>>>(grid, bias, Wt, partial);
    wscan_gemm_kernel<<<2048, 512, 0, stream>>>(grid, Wt, partial, out);
}